// Round 3
// baseline (2574.552 us; speedup 1.0000x reference)
//
#include <hip/hip_runtime.h>
#include <hip/hip_bf16.h>
#include <math.h>

#define NPTS 16384
#define DIM  128
#define TI   64
#define TJ   128
#define PADJ 132   // padded LDS row stride (floats): 16B-aligned, bank-stride 4 -> <=2-way
#define NCLS 10
#define KNN  3

// ---------------- kernel 1: row normalize (matches jnp: x / max(||x||, 1e-8)) ----------
__global__ __launch_bounds__(256) void norm_kernel(const float* __restrict__ X,
                                                   float* __restrict__ Xn) {
  int row  = blockIdx.x * 4 + (threadIdx.x >> 6);
  int lane = threadIdx.x & 63;
  const float* xr = X + (size_t)row * DIM;
  float a = xr[lane];
  float b = xr[lane + 64];
  float ss = a * a + b * b;
#pragma unroll
  for (int off = 32; off > 0; off >>= 1) ss += __shfl_xor(ss, off);
  float nrm = fmaxf(sqrtf(ss), 1e-8f);
  float* o = Xn + (size_t)row * DIM;
  o[lane]      = a / nrm;
  o[lane + 64] = b / nrm;
}

// ---------------- main kernel helpers ----------------
__device__ __forceinline__ void stage_B(const float* __restrict__ Xn,
                                        const int* __restrict__ y, int jt,
                                        float* B, int* yB, int tid) {
#pragma unroll
  for (int rep = 0; rep < 16; ++rep) {
    int idx = rep * 256 + tid;
    int row = idx >> 5, c4 = idx & 31;
    float4 v = *(const float4*)(Xn + (size_t)(jt + row) * DIM + c4 * 4);
    *(float4*)(B + row * PADJ + c4 * 4) = v;
  }
  if (tid < TJ) yB[tid] = y[jt + tid];
}

// IMPORTANT: both passes call this exact function so distances are bit-identical
// (the anchor is one of the pass-1 distances; "<=" must catch it exactly).
__device__ __forceinline__ void compute_tile(const float* A, const float* B,
                                             int ty, int tx, float acc[4][8]) {
#pragma unroll
  for (int r = 0; r < 4; ++r)
#pragma unroll
    for (int c = 0; c < 8; ++c) acc[r][c] = 0.0f;

#pragma unroll 2
  for (int d = 0; d < DIM; d += 4) {
    float4 av[4];
    float4 bv[8];
#pragma unroll
    for (int r = 0; r < 4; ++r)
      av[r] = *(const float4*)(A + (ty * 4 + r) * PADJ + d);
#pragma unroll
    for (int c = 0; c < 8; ++c)
      bv[c] = *(const float4*)(B + (tx + 16 * c) * PADJ + d);
#pragma unroll
    for (int r = 0; r < 4; ++r)
#pragma unroll
      for (int c = 0; c < 8; ++c) {
        acc[r][c] += av[r].x * bv[c].x;
        acc[r][c] += av[r].y * bv[c].y;
        acc[r][c] += av[r].z * bv[c].z;
        acc[r][c] += av[r].w * bv[c].w;
      }
  }
}

// ---------------- kernel 2: fused anchor (top-4 same-class) + in-radius count ----------
__global__ __launch_bounds__(256) void mi_main(const float* __restrict__ Xn,
                                               const int* __restrict__ y,
                                               int* __restrict__ m_out) {
  __shared__ float Ash[TI * PADJ];       // 33.8 KB, resident i-tile
  __shared__ float Bsh[TJ * PADJ];       // 67.6 KB, j-tile
  __shared__ float cand[TI * 16 * 4];    // 16 KB merge buffer (reused as int counts)
  __shared__ int   yAsh[TI];
  __shared__ int   yBsh[TJ];
  __shared__ float anchors[TI];

  int tid = threadIdx.x;
  int tx = tid & 15, ty = tid >> 4;
  int i0 = blockIdx.x * TI;

  // stage resident A tile (64 rows)
#pragma unroll
  for (int rep = 0; rep < 8; ++rep) {
    int idx = rep * 256 + tid;
    int row = idx >> 5, c4 = idx & 31;
    float4 v = *(const float4*)(Xn + (size_t)(i0 + row) * DIM + c4 * 4);
    *(float4*)(Ash + row * PADJ + c4 * 4) = v;
  }
  if (tid < TI) yAsh[tid] = y[i0 + tid];
  __syncthreads();

  int myY[4], myI[4];
#pragma unroll
  for (int r = 0; r < 4; ++r) {
    myY[r] = yAsh[ty * 4 + r];
    myI[r] = i0 + ty * 4 + r;
  }

  // -------- pass 1: per-thread top-4 smallest same-class distances --------
  float top[4][4];
#pragma unroll
  for (int r = 0; r < 4; ++r)
    top[r][0] = top[r][1] = top[r][2] = top[r][3] = 1.0e7f;  // BIG fill, as reference

  for (int jt = 0; jt < NPTS; jt += TJ) {
    __syncthreads();
    stage_B(Xn, y, jt, Bsh, yBsh, tid);
    __syncthreads();
    float acc[4][8];
    compute_tile(Ash, Bsh, ty, tx, acc);
#pragma unroll
    for (int c = 0; c < 8; ++c) {
      int jl = tx + 16 * c;
      int jg = jt + jl;
      int yj = yBsh[jl];
#pragma unroll
      for (int r = 0; r < 4; ++r) {
        float dist = 1.0f - acc[r][c];
        if (jg == myI[r]) dist = 0.0f;  // diagonal exactly 0 (self-pair), as reference
        if (yj == myY[r] && dist < top[r][3]) {
          top[r][3] = dist;
          if (top[r][3] < top[r][2]) { float t = top[r][2]; top[r][2] = top[r][3]; top[r][3] = t; }
          if (top[r][2] < top[r][1]) { float t = top[r][1]; top[r][1] = top[r][2]; top[r][2] = t; }
          if (top[r][1] < top[r][0]) { float t = top[r][0]; top[r][0] = top[r][1]; top[r][1] = t; }
        }
      }
    }
  }

  // -------- merge per-thread top-4 lists -> per-row anchor (4th smallest incl. self=0)
  __syncthreads();
#pragma unroll
  for (int r = 0; r < 4; ++r) {
    int il = ty * 4 + r;
#pragma unroll
    for (int k = 0; k < 4; ++k) cand[il * 64 + tx * 4 + k] = top[r][k];
  }
  __syncthreads();
  if (tid < TI) {
    float t4[4] = {1.0e7f, 1.0e7f, 1.0e7f, 1.0e7f};
    for (int s = 0; s < 64; ++s) {
      float v = cand[tid * 64 + s];
      if (v < t4[3]) {
        t4[3] = v;
        if (t4[3] < t4[2]) { float t = t4[2]; t4[2] = t4[3]; t4[3] = t; }
        if (t4[2] < t4[1]) { float t = t4[1]; t4[1] = t4[2]; t4[2] = t; }
        if (t4[1] < t4[0]) { float t = t4[0]; t4[0] = t4[1]; t4[1] = t; }
      }
    }
    anchors[tid] = t4[3];
  }
  __syncthreads();

  float anch[4];
#pragma unroll
  for (int r = 0; r < 4; ++r) anch[r] = anchors[ty * 4 + r];

  // -------- pass 2: count all-class points within anchor radius (bit-identical dists)
  int cnt[4] = {0, 0, 0, 0};
  for (int jt = 0; jt < NPTS; jt += TJ) {
    __syncthreads();
    stage_B(Xn, y, jt, Bsh, yBsh, tid);
    __syncthreads();
    float acc[4][8];
    compute_tile(Ash, Bsh, ty, tx, acc);
#pragma unroll
    for (int c = 0; c < 8; ++c) {
      int jl = tx + 16 * c;
      int jg = jt + jl;
#pragma unroll
      for (int r = 0; r < 4; ++r) {
        float dist = 1.0f - acc[r][c];
        if (jg == myI[r]) dist = 0.0f;
        cnt[r] += (dist <= anch[r]) ? 1 : 0;
      }
    }
  }

  __syncthreads();
  int* icnt = (int*)cand;
#pragma unroll
  for (int r = 0; r < 4; ++r) icnt[(ty * 4 + r) * 16 + tx] = cnt[r];
  __syncthreads();
  if (tid < TI) {
    int s = 0;
#pragma unroll
    for (int k = 0; k < 16; ++k) s += icnt[tid * 16 + k];
    m_out[i0 + tid] = s - 1;  // subtract self
  }
}

// ---------------- kernel 3: digamma terms + final scalar ----------------
__device__ double digamma_d(double x) {
  double r = 0.0;
  while (x < 10.0) { r -= 1.0 / x; x += 1.0; }
  double inv = 1.0 / x, inv2 = inv * inv;
  double s = log(x) - 0.5 * inv;
  double p = inv2;
  s -= p * (1.0 / 12.0);
  p *= inv2; s += p * (1.0 / 120.0);
  p *= inv2; s -= p * (1.0 / 252.0);
  p *= inv2; s += p * (1.0 / 240.0);
  p *= inv2; s -= p * (1.0 / 132.0);
  return s + r;
}

__global__ __launch_bounds__(256) void finalize_kernel(const int* __restrict__ m,
                                                       const int* __restrict__ y,
                                                       float* __restrict__ out) {
  __shared__ double sm[256];
  __shared__ int hist[NCLS];
  int tid = threadIdx.x;
  if (tid < NCLS) hist[tid] = 0;
  __syncthreads();
  for (int i = tid; i < NPTS; i += 256) atomicAdd(&hist[y[i]], 1);  // int atomics: deterministic
  double s = 0.0;
  for (int i = tid; i < NPTS; i += 256) s += digamma_d((double)m[i]);
  sm[tid] = s;
  __syncthreads();
  for (int st = 128; st > 0; st >>= 1) {
    if (tid < st) sm[tid] += sm[tid + st];
    __syncthreads();
  }
  if (tid == 0) {
    double avg_m = sm[0] / (double)NPTS;
    double avg_N_x = 0.0;
    for (int c = 0; c < NCLS; ++c) {
      double cf = (double)hist[c];
      avg_N_x += (cf / (double)NPTS) * digamma_d(cf);
    }
    double mi = digamma_d((double)NPTS) - avg_N_x + digamma_d((double)KNN) - avg_m;
    out[0] = (float)(mi / log(2.0));
  }
}

// ---------------- launcher ----------------
extern "C" void kernel_launch(void* const* d_in, const int* in_sizes, int n_in,
                              void* d_out, int out_size, void* d_ws, size_t ws_size,
                              hipStream_t stream) {
  const float* X = (const float*)d_in[0];
  const int*   y = (const int*)d_in[1];
  float* out = (float*)d_out;

  float* Xn = (float*)d_ws;                                         // 8 MB
  int*   m  = (int*)((char*)d_ws + (size_t)NPTS * DIM * sizeof(float));  // 64 KB

  norm_kernel<<<NPTS / 4, 256, 0, stream>>>(X, Xn);
  mi_main<<<NPTS / TI, 256, 0, stream>>>(Xn, y, m);
  finalize_kernel<<<1, 256, 0, stream>>>(m, y, out);
}

// Round 5
// 836.962 us; speedup vs baseline: 3.0761x; 3.0761x over previous
//
#include <hip/hip_runtime.h>
#include <hip/hip_bf16.h>
#include <math.h>

#define NPTS 16384
#define DIM  128
#define NCLS 10
#define KNN  3
#define Q    8            // j-range splits
#define JR   (NPTS/Q)     // 2048 per block
#define TJ   64           // j-tile staged in LDS
#define EPS  2.5e-5f      // hard bound on |approx_dist - exact_fp32_dist| (~1.3e-5) + margin
#define CAP  (1<<20)
#define NC   (Q*2*6)      // candidates per row = 96

typedef float  f16v __attribute__((ext_vector_type(16)));
typedef __bf16 bf8v __attribute__((ext_vector_type(8)));

// ---------------- K1: normalize + bf16 hi/lo split ----------------
__global__ __launch_bounds__(256) void prep_kernel(const float* __restrict__ X,
                                                   float* __restrict__ Xn,
                                                   ushort* __restrict__ Hi,
                                                   ushort* __restrict__ Lo) {
  int row  = blockIdx.x * 4 + (threadIdx.x >> 6);
  int lane = threadIdx.x & 63;
  const float* xr = X + (size_t)row * DIM;
  float a = xr[lane], b = xr[lane + 64];
  float ss = a * a + b * b;
#pragma unroll
  for (int off = 32; off > 0; off >>= 1) ss += __shfl_xor(ss, off);
  float nrm = fmaxf(sqrtf(ss), 1e-8f);
  float an = a / nrm, bn = b / nrm;
  Xn[(size_t)row * DIM + lane]      = an;
  Xn[(size_t)row * DIM + lane + 64] = bn;
  __hip_bfloat16 ha = __float2bfloat16(an);
  __hip_bfloat16 hb = __float2bfloat16(bn);
  __hip_bfloat16 la = __float2bfloat16(an - __bfloat162float(ha));
  __hip_bfloat16 lb = __float2bfloat16(bn - __bfloat162float(hb));
  Hi[(size_t)row * DIM + lane]      = *(ushort*)&ha;
  Hi[(size_t)row * DIM + lane + 64] = *(ushort*)&hb;
  Lo[(size_t)row * DIM + lane]      = *(ushort*)&la;
  Lo[(size_t)row * DIM + lane + 64] = *(ushort*)&lb;
}

// ---------------- K1b: pack classes 4-bit ----------------
__global__ void pack_y(const int* __restrict__ y, uint* __restrict__ yp) {
  int g = blockIdx.x * 256 + threadIdx.x;
  if (g < NPTS / 8) {
    uint w = 0;
#pragma unroll
    for (int k = 0; k < 8; ++k) w |= ((uint)y[g * 8 + k] & 15u) << (4 * k);
    yp[g] = w;
  }
}

// ---------------- shared MFMA tile helper (identical in pass1/pass2) ----------------
// A-operand = j-points (rows of C), B-operand = i-rows (cols of C).
// C mapping (32x32x16): col = lane&31 (one i-row per lane), row = (r&3)+8*(r>>2)+4*(lane>>5).
__device__ __forceinline__ f16v tile_mfma(const float4* BH, const float4* BL,
                                          const bf8v bhi[8], const bf8v blo[8],
                                          int lrow, int h) {
  f16v acc = {0,0,0,0,0,0,0,0,0,0,0,0,0,0,0,0};
  int rswz = lrow & 15;
  bf8v ah[8], al[8];
#pragma unroll
  for (int c = 0; c < 8; ++c) {
    int sl = c * 2 + h;
    ah[c] = ((const bf8v*)BH)[lrow * 16 + (sl ^ rswz)];
  }
#pragma unroll
  for (int c = 0; c < 8; ++c)
    acc = __builtin_amdgcn_mfma_f32_32x32x16_bf16(ah[c], bhi[c], acc, 0, 0, 0);
#pragma unroll
  for (int c = 0; c < 8; ++c) {
    int sl = c * 2 + h;
    al[c] = ((const bf8v*)BL)[lrow * 16 + (sl ^ rswz)];
  }
#pragma unroll
  for (int c = 0; c < 8; ++c)
    acc = __builtin_amdgcn_mfma_f32_32x32x16_bf16(al[c], bhi[c], acc, 0, 0, 0);
#pragma unroll
  for (int c = 0; c < 8; ++c)
    acc = __builtin_amdgcn_mfma_f32_32x32x16_bf16(ah[c], blo[c], acc, 0, 0, 0);
  return acc;
}

__device__ __forceinline__ void stage_tile(const ushort* __restrict__ Hi,
                                           const ushort* __restrict__ Lo,
                                           int j0, float4* BH, float4* BL, int tid) {
#pragma unroll
  for (int k = 0; k < 4; ++k) {
    int s = tid + 256 * k;
    int row = s >> 4, sl = s & 15;
    size_t gb = ((size_t)(j0 + row)) * 256 + sl * 16;
    BH[row * 16 + (sl ^ (row & 15))] = *(const float4*)((const char*)Hi + gb);
    BL[row * 16 + (sl ^ (row & 15))] = *(const float4*)((const char*)Lo + gb);
  }
}

// ---------------- K2: pass 1 — approx per-lane top-6 same-class (by dot) ----------------
__global__ __launch_bounds__(256) void pass1_kernel(const ushort* __restrict__ Hi,
                                                    const ushort* __restrict__ Lo,
                                                    const uint* __restrict__ yp,
                                                    const int* __restrict__ y,
                                                    int* __restrict__ candj) {
  __shared__ float4 BH[TJ * 16];
  __shared__ float4 BL[TJ * 16];
  int tid = threadIdx.x;
  int wave = tid >> 6, lane = tid & 63;
  int col = lane & 31, h = lane >> 5;
  int rb = blockIdx.x >> 3, q = blockIdx.x & 7;
  int irow = rb * 128 + wave * 32 + col;
  int myc = y[irow];
  int rlo = rb * 128, rhi = rlo + 128;

  bf8v bhi[8], blo[8];
#pragma unroll
  for (int c = 0; c < 8; ++c) {
    bhi[c] = *(const bf8v*)(Hi + (size_t)irow * DIM + c * 16 + h * 8);
    blo[c] = *(const bf8v*)(Lo + (size_t)irow * DIM + c * 16 + h * 8);
  }

  float t0=-3e38f,t1=-3e38f,t2=-3e38f,t3=-3e38f,t4=-3e38f,t5=-3e38f;
  int   j0=-1,j1=-1,j2=-1,j3=-1,j4=-1,j5=-1;

  int jq = q * JR;
  for (int jt = 0; jt < JR; jt += TJ) {
    __syncthreads();
    stage_tile(Hi, Lo, jq + jt, BH, BL, tid);
    __syncthreads();
#pragma unroll
    for (int js = 0; js < 2; ++js) {
      int jbase = jq + jt + js * 32;
      const uint* cw = yp + (jbase >> 3);
      uint w0 = cw[0], w1 = cw[1], w2 = cw[2], w3 = cw[3];
      f16v acc = tile_mfma(BH, BL, bhi, blo, js * 32 + col, h);
      bool dodiag = (jbase < rhi) && (jbase + 32 > rlo);
#pragma unroll
      for (int r = 0; r < 16; ++r) {
        int jrow = (r & 3) + 8 * (r >> 2) + 4 * h;
        int jg = jbase + jrow;
        uint wsel = (r >> 2) == 0 ? w0 : ((r >> 2) == 1 ? w1 : ((r >> 2) == 2 ? w2 : w3));
        int cls = (int)((wsel >> ((jrow & 7) * 4)) & 15u);
        float dot = acc[r];
        if (dodiag && jg == irow) dot = 2.0f;   // self sentinel: guaranteed top
        if (cls == myc && dot > t5) {
          t5 = dot; j5 = jg;
          if (t5 > t4) { float v=t4;t4=t5;t5=v; int j=j4;j4=j5;j5=j; }
          if (t4 > t3) { float v=t3;t3=t4;t4=v; int j=j3;j3=j4;j4=j; }
          if (t3 > t2) { float v=t2;t2=t3;t3=v; int j=j2;j2=j3;j3=j; }
          if (t2 > t1) { float v=t1;t1=t2;t2=v; int j=j1;j1=j2;j2=j; }
          if (t1 > t0) { float v=t0;t0=t1;t1=v; int j=j0;j0=j1;j1=j; }
        }
      }
    }
  }
  size_t base = (((size_t)irow * Q + q) * 2 + h) * 6;
  candj[base+0]=j0; candj[base+1]=j1; candj[base+2]=j2;
  candj[base+3]=j3; candj[base+4]=j4; candj[base+5]=j5;
}

// ---------------- K3: exact fp32 anchors from candidates ----------------
__global__ __launch_bounds__(256) void anchor_kernel(const float* __restrict__ Xn,
                                                     const int* __restrict__ candj,
                                                     float* __restrict__ anchors) {
  __shared__ float xi[4][DIM];
  int wave = threadIdx.x >> 6, lane = threadIdx.x & 63;
  int row = blockIdx.x * 4 + wave;
  xi[wave][lane]      = Xn[(size_t)row * DIM + lane];
  xi[wave][lane + 64] = Xn[(size_t)row * DIM + lane + 64];
  __syncthreads();
  float d0 = 1e30f, d1 = 1e30f;
  int k0 = lane, k1 = lane + 64;
#pragma unroll
  for (int sl = 0; sl < 2; ++sl) {
    int k = sl == 0 ? k0 : k1;
    float dist = 1e30f;
    if (k < NC) {
      int idx = candj[(size_t)row * NC + k];
      if (idx == row) dist = 0.0f;               // self: exactly 0, as reference
      else if (idx >= 0) {
        const float* xj = Xn + (size_t)idx * DIM;
        float acc = 0.f;
        for (int dd = 0; dd < DIM; dd += 4) {    // linear order = refine/anchor consistency
          float4 b = *(const float4*)(xj + dd);
          acc += xi[wave][dd+0] * b.x;
          acc += xi[wave][dd+1] * b.y;
          acc += xi[wave][dd+2] * b.z;
          acc += xi[wave][dd+3] * b.w;
        }
        dist = 1.0f - acc;
      }
    }
    if (sl == 0) d0 = dist; else d1 = dist;
  }
  float m = 0.f;
  for (int t = 0; t < 4; ++t) {                  // 4th smallest (K+1 incl self)
    float g = fminf(d0, d1);
#pragma unroll
    for (int off = 32; off > 0; off >>= 1) g = fminf(g, __shfl_xor(g, off));
    int kc = 0x7fffffff;
    if (d0 == g) kc = k0;
    if (d1 == g && k1 < kc) kc = k1;
#pragma unroll
    for (int off = 32; off > 0; off >>= 1) kc = min(kc, __shfl_xor(kc, off));
    if (k0 == kc) d0 = 1e30f;
    if (k1 == kc) d1 = 1e30f;
    m = g;
  }
  if (lane == 0) anchors[row] = m;
}

// ---------------- K4: pass 2 — definite count + borderline flags ----------------
__global__ __launch_bounds__(256) void pass2_kernel(const ushort* __restrict__ Hi,
                                                    const ushort* __restrict__ Lo,
                                                    const float* __restrict__ anchors,
                                                    int* __restrict__ mcnt,
                                                    uint* __restrict__ ticket,
                                                    uint* __restrict__ flags) {
  __shared__ float4 BH[TJ * 16];
  __shared__ float4 BL[TJ * 16];
  int tid = threadIdx.x;
  int wave = tid >> 6, lane = tid & 63;
  int col = lane & 31, h = lane >> 5;
  int rb = blockIdx.x >> 3, q = blockIdx.x & 7;
  int irow = rb * 128 + wave * 32 + col;
  int rlo = rb * 128, rhi = rlo + 128;
  float anch = anchors[irow];

  bf8v bhi[8], blo[8];
#pragma unroll
  for (int c = 0; c < 8; ++c) {
    bhi[c] = *(const bf8v*)(Hi + (size_t)irow * DIM + c * 16 + h * 8);
    blo[c] = *(const bf8v*)(Lo + (size_t)irow * DIM + c * 16 + h * 8);
  }

  int cnt = 0;
  int jq = q * JR;
  for (int jt = 0; jt < JR; jt += TJ) {
    __syncthreads();
    stage_tile(Hi, Lo, jq + jt, BH, BL, tid);
    __syncthreads();
#pragma unroll
    for (int js = 0; js < 2; ++js) {
      int jbase = jq + jt + js * 32;
      f16v acc = tile_mfma(BH, BL, bhi, blo, js * 32 + col, h);
      bool dodiag = (jbase < rhi) && (jbase + 32 > rlo);
#pragma unroll
      for (int r = 0; r < 16; ++r) {
        int jrow = (r & 3) + 8 * (r >> 2) + 4 * h;
        int jg = jbase + jrow;
        float dot = acc[r];
        if (dodiag && jg == irow) dot = 2.0f;    // self: dist -1 => definite in
        float dist = 1.0f - dot;
        if (dist <= anch - EPS) cnt++;
        else if (dist <= anch + EPS) {
          uint t = atomicAdd(ticket, 1u);
          if (t < CAP) flags[t] = ((uint)irow << 14) | (uint)jg;
        }
      }
    }
  }
  atomicAdd(&mcnt[irow], cnt);
}

// ---------------- K5: exact refinement of borderline pairs ----------------
__global__ __launch_bounds__(256) void refine_kernel(const float* __restrict__ Xn,
                                                     const float* __restrict__ anchors,
                                                     const uint* __restrict__ ticket,
                                                     const uint* __restrict__ flags,
                                                     int* __restrict__ mcnt) {
  uint n = *ticket; if (n > CAP) n = CAP;
  for (uint idx = blockIdx.x * 256 + threadIdx.x; idx < n; idx += gridDim.x * 256) {
    uint pk = flags[idx];
    int i = (int)(pk >> 14), j = (int)(pk & 16383u);
    const float* xi = Xn + (size_t)i * DIM;
    const float* xj = Xn + (size_t)j * DIM;
    float acc = 0.f;
    for (int d = 0; d < DIM; d += 4) {           // same linear order as anchor_kernel
      float4 a = *(const float4*)(xi + d);
      float4 b = *(const float4*)(xj + d);
      acc += a.x * b.x; acc += a.y * b.y; acc += a.z * b.z; acc += a.w * b.w;
    }
    float dist = 1.0f - acc;
    if (dist <= anchors[i]) atomicAdd(&mcnt[i], 1);
  }
}

// ---------------- K6: digammas + final scalar ----------------
__device__ double digamma_d(double x) {
  double r = 0.0;
  while (x < 10.0) { r -= 1.0 / x; x += 1.0; }
  double inv = 1.0 / x, inv2 = inv * inv;
  double s = log(x) - 0.5 * inv;
  double p = inv2;
  s -= p * (1.0 / 12.0);
  p *= inv2; s += p * (1.0 / 120.0);
  p *= inv2; s -= p * (1.0 / 252.0);
  p *= inv2; s += p * (1.0 / 240.0);
  p *= inv2; s -= p * (1.0 / 132.0);
  return s + r;
}

__global__ __launch_bounds__(256) void finalize_kernel(const int* __restrict__ mcnt,
                                                       const int* __restrict__ y,
                                                       float* __restrict__ out) {
  __shared__ double sm[256];
  __shared__ int hist[NCLS];
  int tid = threadIdx.x;
  if (tid < NCLS) hist[tid] = 0;
  __syncthreads();
  for (int i = tid; i < NPTS; i += 256) atomicAdd(&hist[y[i]], 1);
  double s = 0.0;
  for (int i = tid; i < NPTS; i += 256) s += digamma_d((double)(mcnt[i] - 1)); // -1: self
  sm[tid] = s;
  __syncthreads();
  for (int st = 128; st > 0; st >>= 1) {
    if (tid < st) sm[tid] += sm[tid + st];
    __syncthreads();
  }
  if (tid == 0) {
    double avg_m = sm[0] / (double)NPTS;
    double avg_N_x = 0.0;
    for (int c = 0; c < NCLS; ++c) {
      double cf = (double)hist[c];
      avg_N_x += (cf / (double)NPTS) * digamma_d(cf);
    }
    double mi = digamma_d((double)NPTS) - avg_N_x + digamma_d((double)KNN) - avg_m;
    out[0] = (float)(mi / log(2.0));
  }
}

// ---------------- launcher ----------------
extern "C" void kernel_launch(void* const* d_in, const int* in_sizes, int n_in,
                              void* d_out, int out_size, void* d_ws, size_t ws_size,
                              hipStream_t stream) {
  const float* X = (const float*)d_in[0];
  const int*   y = (const int*)d_in[1];
  float* out = (float*)d_out;
  char* ws = (char*)d_ws;

  float*  Xn      = (float*)(ws);                         // 8 MB
  ushort* Hi      = (ushort*)(ws + (8u << 20));           // 4 MB
  ushort* Lo      = (ushort*)(ws + (12u << 20));          // 4 MB
  int*    candj   = (int*)(ws + (16u << 20));             // 16384*96*4 = 6 MB
  char*   p       = ws + (16u << 20) + (size_t)NPTS * NC * 4;
  float*  anchors = (float*)(p);            p += (size_t)NPTS * 4;
  int*    mcnt    = (int*)(p);              p += (size_t)NPTS * 4;
  uint*   yp      = (uint*)(p);             p += (NPTS / 8) * 4;
  uint*   ticket  = (uint*)(p);             p += 256;
  uint*   flags   = (uint*)(p);                           // 4 MB

  hipMemsetAsync(mcnt, 0, NPTS * sizeof(int), stream);
  hipMemsetAsync(ticket, 0, sizeof(uint), stream);

  prep_kernel<<<NPTS / 4, 256, 0, stream>>>(X, Xn, Hi, Lo);
  pack_y<<<(NPTS / 8 + 255) / 256, 256, 0, stream>>>(y, yp);
  pass1_kernel<<<(NPTS / 128) * Q, 256, 0, stream>>>(Hi, Lo, yp, y, candj);
  anchor_kernel<<<NPTS / 4, 256, 0, stream>>>(Xn, candj, anchors);
  pass2_kernel<<<(NPTS / 128) * Q, 256, 0, stream>>>(Hi, Lo, anchors, mcnt, ticket, flags);
  refine_kernel<<<256, 256, 0, stream>>>(Xn, anchors, ticket, flags, mcnt);
  finalize_kernel<<<1, 256, 0, stream>>>(mcnt, y, out);
}